// Round 2
// baseline (562.398 us; speedup 1.0000x reference)
//
#include <hip/hip_runtime.h>
#include <hip/hip_bf16.h>

#define NB 2048
#define NF 6144
#define ND 768
#define NT (NF / 64)  // 96 K-steps per layer

typedef __attribute__((ext_vector_type(8))) __bf16 bf16x8;
typedef __attribute__((ext_vector_type(4))) float f32x4;

// LDS tile: 128 rows x 64 bf16 (128 B rows). 16B-block swizzle:
//   blk_stored = (k>>3) ^ (row&7) ^ ((row>>2)&7)
// Verified by hand: fragment ds_read_b128 (16 consecutive rows x 4 k-blocks),
// A-staging writes (8 rows x 8 k-blocks) and B-staging writes (rows 4*l+dd)
// all land at the 8-bank-cycle minimum for 1 KB/inst.
__device__ __forceinline__ char* lds_addr(char* base, int row, int k) {
  const int blk = ((k >> 3) ^ (row & 7) ^ ((row >> 2) & 7)) & 7;
  return base + row * 128 + (blk << 4) + ((k & 7) << 1);
}

// out[b,d] = sum_l bias[l,d]  (also clears the 0xAA poison deterministically)
__global__ __launch_bounds__(256) void bias_init_kernel(
    const float* __restrict__ bias, const int* __restrict__ lidx,
    float* __restrict__ out) {
  int n = lidx[0] + 1;
  int i = blockIdx.x * 256 + threadIdx.x;
  if (i >= NB * ND) return;
  int d = i % ND;
  float s = 0.f;
  for (int l = 0; l < n; ++l) s += bias[l * ND + d];
  out[i] = s;
}

__global__ __launch_bounds__(256, 2) void gemm_kernel(
    const float* __restrict__ acts, const float* __restrict__ W,
    const int* __restrict__ lidx, float* __restrict__ out) {
  const int l = blockIdx.z;
  if (l > lidx[0]) return;  // uniform exit before any barrier

  const int brow = blockIdx.x * 128;
  const int ncol = blockIdx.y * 128;

  __shared__ char cA[128 * 128];  // 128 rows(b) x 64 bf16(k)
  __shared__ char cB[128 * 128];  // 128 rows(d) x 64 bf16(k)

  const int tid = threadIdx.x;
  const int lane = tid & 63;
  const int wid = tid >> 6;
  const int wrow = (wid >> 1) * 64;  // wave's 64x64 sub-tile
  const int wcol = (wid & 1) * 64;

  f32x4 acc[4][4];
#pragma unroll
  for (int i = 0; i < 4; ++i)
#pragma unroll
    for (int j = 0; j < 4; ++j) acc[i][j] = (f32x4){0.f, 0.f, 0.f, 0.f};

  // A staging: thread -> (row = tid>>3 (+32 per pass p), 8 consecutive k)
  const int s_arow = tid >> 3;        // 0..31
  const int s_ak = (tid & 7) * 8;     // 0,8,...,56
  // B staging: thread -> (4 consecutive d = (tid&31)*4.., 8 consecutive k)
  const int s_bd = (tid & 31) * 4;    // 0..124
  const int s_bk = (tid >> 5) * 8;    // 0,8,...,56

  const float* Aptr =
      acts + (size_t)l * NB * NF + (size_t)(brow + s_arow) * NF + s_ak;
  const float* Bptr =
      W + (size_t)l * NF * ND + (size_t)s_bk * ND + (ncol + s_bd);

  float4 av[4][2];  // 4 row-passes x 8 k (fp32)
  float4 bv[8];     // 8 k-rows x 4 d (fp32)

  auto LOADS = [&](int kb) {
#pragma unroll
    for (int p = 0; p < 4; ++p) {
      av[p][0] = *(const float4*)(Aptr + (size_t)(32 * p) * NF + kb);
      av[p][1] = *(const float4*)(Aptr + (size_t)(32 * p) * NF + kb + 4);
    }
#pragma unroll
    for (int j = 0; j < 8; ++j)
      bv[j] = *(const float4*)(Bptr + (size_t)(kb + j) * ND);
  };

  auto STORE = [&]() {
#pragma unroll
    for (int p = 0; p < 4; ++p) {
      bf16x8 h;
      h[0] = (__bf16)av[p][0].x; h[1] = (__bf16)av[p][0].y;
      h[2] = (__bf16)av[p][0].z; h[3] = (__bf16)av[p][0].w;
      h[4] = (__bf16)av[p][1].x; h[5] = (__bf16)av[p][1].y;
      h[6] = (__bf16)av[p][1].z; h[7] = (__bf16)av[p][1].w;
      *(bf16x8*)lds_addr(cA, s_arow + 32 * p, s_ak) = h;
    }
#pragma unroll
    for (int dd = 0; dd < 4; ++dd) {
      bf16x8 h;
#pragma unroll
      for (int j = 0; j < 8; ++j) h[j] = (__bf16)bv[j][dd];
      *(bf16x8*)lds_addr(cB, s_bd + dd, s_bk) = h;
    }
  };

  LOADS(0);

  for (int kt = 0; kt < NT; ++kt) {
    __syncthreads();  // previous iteration's fragment reads are done
    STORE();          // cvt fp32->bf16 + swizzled LDS write (waits vmcnt)
    if (kt + 1 < NT) LOADS((kt + 1) * 64);  // next slab in flight during MFMA
    __syncthreads();

    // ---- MFMA: 2 k-steps of 32, 4x4 fragments (covers the load latency) ----
#pragma unroll
    for (int s = 0; s < 2; ++s) {
      const int kk = s * 32 + (lane >> 4) * 8;  // this lane's k origin
      bf16x8 aF[4], bF[4];
#pragma unroll
      for (int mi = 0; mi < 4; ++mi)
        aF[mi] = *(const bf16x8*)lds_addr(cA, wrow + mi * 16 + (lane & 15), kk);
#pragma unroll
      for (int ni = 0; ni < 4; ++ni)
        bF[ni] = *(const bf16x8*)lds_addr(cB, wcol + ni * 16 + (lane & 15), kk);
#pragma unroll
      for (int mi = 0; mi < 4; ++mi)
#pragma unroll
        for (int ni = 0; ni < 4; ++ni)
          acc[mi][ni] = __builtin_amdgcn_mfma_f32_16x16x32_bf16(
              aF[mi], bF[ni], acc[mi][ni], 0, 0, 0);
    }
  }

  // ---- epilogue: atomic accumulate into out (12 layer-blocks collide) ----
  // C/D layout (m89-verified): col = lane&15, row = (lane>>4)*4 + j
  const int orow = brow + wrow + ((lane >> 4) << 2);
  const int ocol = ncol + wcol + (lane & 15);
#pragma unroll
  for (int mi = 0; mi < 4; ++mi)
#pragma unroll
    for (int ni = 0; ni < 4; ++ni)
#pragma unroll
      for (int j = 0; j < 4; ++j)
        atomicAdd(out + (size_t)(orow + mi * 16 + j) * ND + (ocol + ni * 16),
                  acc[mi][ni][j]);
}

extern "C" void kernel_launch(void* const* d_in, const int* in_sizes, int n_in,
                              void* d_out, int out_size, void* d_ws, size_t ws_size,
                              hipStream_t stream) {
  const float* acts = (const float*)d_in[0];
  const float* W    = (const float*)d_in[1];
  const float* bias = (const float*)d_in[2];
  const int*   lidx = (const int*)d_in[3];
  float* out = (float*)d_out;

  const int L = in_sizes[0] / (NB * NF);  // 12

  bias_init_kernel<<<dim3((NB * ND + 255) / 256), 256, 0, stream>>>(bias, lidx, out);
  gemm_kernel<<<dim3(NB / 128, ND / 128, L), 256, 0, stream>>>(acts, W, lidx, out);
}